// Round 1
// baseline (7415.069 us; speedup 1.0000x reference)
//
#include <hip/hip_runtime.h>
#include <math.h>

#define BN 1024
#define TT 128
#define DD 64
#define HH 256
#define H3 768
#define BB 4

// Transposed weights live in module globals: no dependence on ws_size,
// written by prep_kernel every call (deterministic, graph-capture safe).
__device__ float g_W1t[HH * HH];   // [k][i] = W1[i][k]
__device__ float g_W2t[HH * HH];   // [k][i] = W2[i][k]
__device__ float g_Whht[HH * H3];  // [k][j] = W_hh[j][k]
__device__ float g_Wiht[DD * H3];  // [k][j] = W_ih[j][k]

__global__ __launch_bounds__(256) void prep_kernel(
    const float* __restrict__ W1, const float* __restrict__ W2,
    const float* __restrict__ Whh, const float* __restrict__ Wih)
{
  const int idx = blockIdx.x * blockDim.x + threadIdx.x;
  if (idx < HH * HH) {
    const int k = idx >> 8;        // idx / HH
    const int i = idx & (HH - 1);  // idx % HH
    g_W1t[idx] = W1[i * HH + k];
    g_W2t[idx] = W2[i * HH + k];
  }
  if (idx < HH * H3) {
    const int k = idx / H3;
    const int j = idx - k * H3;
    g_Whht[idx] = Whh[j * HH + k];
  }
  if (idx < DD * H3) {
    const int k = idx / H3;
    const int j = idx - k * H3;
    g_Wiht[idx] = Wih[j * DD + k];
  }
}

// acc[bb] = sum_k WT[k*HH + i] * INBUF[k][bb]
#define MV256(WT, INBUF, ACC) do {                                         \
    ACC[0] = 0.0f; ACC[1] = 0.0f; ACC[2] = 0.0f; ACC[3] = 0.0f;            \
    const float* wp_ = &(WT)[i];                                           \
    _Pragma("unroll 8")                                                    \
    for (int k_ = 0; k_ < HH; ++k_) {                                      \
      const float w_ = wp_[k_ * HH];                                       \
      const float4 hv_ = *reinterpret_cast<const float4*>(&(INBUF)[k_][0]);\
      ACC[0] = fmaf(w_, hv_.x, ACC[0]);                                    \
      ACC[1] = fmaf(w_, hv_.y, ACC[1]);                                    \
      ACC[2] = fmaf(w_, hv_.z, ACC[2]);                                    \
      ACC[3] = fmaf(w_, hv_.w, ACC[3]);                                    \
    }                                                                      \
  } while (0)

// KV = f(INBUF) = relu(INBUF @ W1.T + b1) @ W2.T + b2   (per thread: dim i, 4 batch rows)
#define FEVAL(INBUF, KV) do {                                              \
    float a_[BB];                                                          \
    MV256(g_W1t, INBUF, a_);                                               \
    _Pragma("unroll")                                                      \
    for (int bb_ = 0; bb_ < BB; ++bb_)                                     \
      sh_u[i][bb_] = fmaxf(a_[bb_] + b1i, 0.0f);                           \
    __syncthreads();                                                       \
    MV256(g_W2t, sh_u, a_);                                                \
    _Pragma("unroll")                                                      \
    for (int bb_ = 0; bb_ < BB; ++bb_) KV[bb_] = a_[bb_] + b2i;            \
  } while (0)

__global__ __launch_bounds__(256) void odegru_kernel(
    const float* __restrict__ x, const float* __restrict__ times,
    const float* __restrict__ mask,
    const float* __restrict__ b1, const float* __restrict__ b2,
    const float* __restrict__ bih, const float* __restrict__ bhh,
    float* __restrict__ out)
{
  const int i = threadIdx.x;        // output dim 0..255
  const int bbase = blockIdx.x * BB;

  __shared__ __align__(16) float sh_h[HH][BB];   // current h
  __shared__ __align__(16) float sh_in[HH][BB];  // f input / h_ode
  __shared__ __align__(16) float sh_u[HH][BB];   // relu intermediate
  __shared__ __align__(16) float sh_x[DD][BB];   // x[:, t, :]

  const float b1i = b1[i];
  const float b2i = b2[i];
  const float bihr = bih[i], bihz = bih[i + HH], bihn = bih[i + 2 * HH];
  const float bhhr = bhh[i], bhhz = bhh[i + HH], bhhn = bhh[i + 2 * HH];

#pragma unroll
  for (int bb = 0; bb < BB; ++bb) sh_h[i][bb] = 0.0f;

  for (int t = 0; t < TT; ++t) {
    // stage x[:, t, :] for this block's 4 rows
    {
      const int bb = i >> 6, d = i & 63;
      sh_x[d][bb] = x[((size_t)(bbase + bb) * TT + t) * DD + d];
    }
    if (t == 0) {
#pragma unroll
      for (int bb = 0; bb < BB; ++bb) sh_in[i][bb] = 0.0f;  // h_ode = h0 = 0
    }
    __syncthreads();

    if (t > 0) {
      const float dt = times[t] - times[t - 1];
      float kv[BB], ks[BB];

      // ---- k1 ----
      FEVAL(sh_h, kv);
#pragma unroll
      for (int bb = 0; bb < BB; ++bb) {
        ks[bb] = kv[bb];
        sh_in[i][bb] = sh_h[i][bb] + 0.5f * dt * kv[bb];
      }
      __syncthreads();
      // ---- k2 ----
      FEVAL(sh_in, kv);
#pragma unroll
      for (int bb = 0; bb < BB; ++bb) {
        ks[bb] += 2.0f * kv[bb];
        sh_in[i][bb] = sh_h[i][bb] + 0.5f * dt * kv[bb];
      }
      __syncthreads();
      // ---- k3 ----
      FEVAL(sh_in, kv);
#pragma unroll
      for (int bb = 0; bb < BB; ++bb) {
        ks[bb] += 2.0f * kv[bb];
        sh_in[i][bb] = sh_h[i][bb] + dt * kv[bb];
      }
      __syncthreads();
      // ---- k4 ----
      FEVAL(sh_in, kv);
#pragma unroll
      for (int bb = 0; bb < BB; ++bb) {
        ks[bb] += kv[bb];
        sh_in[i][bb] = sh_h[i][bb] + (dt * (1.0f / 6.0f)) * ks[bb];  // h_ode
      }
      __syncthreads();
    }

    // ---- GRU update: input h_ode is in sh_in ----
    float racc[BB], zacc[BB], ghn[BB], gin[BB];
#pragma unroll
    for (int bb = 0; bb < BB; ++bb) {
      racc[bb] = bihr + bhhr;
      zacc[bb] = bihz + bhhz;
      ghn[bb] = bhhn;   // h-side n preactivation (kept separate: n uses r*h_n)
      gin[bb] = bihn;   // x-side n preactivation
    }

    {
      const float* wp = &g_Whht[i];
#pragma unroll 4
      for (int k = 0; k < HH; ++k) {
        const float4 hv = *reinterpret_cast<const float4*>(&sh_in[k][0]);
        const float wr = wp[k * H3];
        const float wz = wp[k * H3 + HH];
        const float wn = wp[k * H3 + 2 * HH];
        racc[0] = fmaf(wr, hv.x, racc[0]); racc[1] = fmaf(wr, hv.y, racc[1]);
        racc[2] = fmaf(wr, hv.z, racc[2]); racc[3] = fmaf(wr, hv.w, racc[3]);
        zacc[0] = fmaf(wz, hv.x, zacc[0]); zacc[1] = fmaf(wz, hv.y, zacc[1]);
        zacc[2] = fmaf(wz, hv.z, zacc[2]); zacc[3] = fmaf(wz, hv.w, zacc[3]);
        ghn[0] = fmaf(wn, hv.x, ghn[0]); ghn[1] = fmaf(wn, hv.y, ghn[1]);
        ghn[2] = fmaf(wn, hv.z, ghn[2]); ghn[3] = fmaf(wn, hv.w, ghn[3]);
      }
    }
    {
      const float* wp = &g_Wiht[i];
#pragma unroll 4
      for (int k = 0; k < DD; ++k) {
        const float4 xv = *reinterpret_cast<const float4*>(&sh_x[k][0]);
        const float wr = wp[k * H3];
        const float wz = wp[k * H3 + HH];
        const float wn = wp[k * H3 + 2 * HH];
        racc[0] = fmaf(wr, xv.x, racc[0]); racc[1] = fmaf(wr, xv.y, racc[1]);
        racc[2] = fmaf(wr, xv.z, racc[2]); racc[3] = fmaf(wr, xv.w, racc[3]);
        zacc[0] = fmaf(wz, xv.x, zacc[0]); zacc[1] = fmaf(wz, xv.y, zacc[1]);
        zacc[2] = fmaf(wz, xv.z, zacc[2]); zacc[3] = fmaf(wz, xv.w, zacc[3]);
        gin[0] = fmaf(wn, xv.x, gin[0]); gin[1] = fmaf(wn, xv.y, gin[1]);
        gin[2] = fmaf(wn, xv.z, gin[2]); gin[3] = fmaf(wn, xv.w, gin[3]);
      }
    }

#pragma unroll
    for (int bb = 0; bb < BB; ++bb) {
      const float r = 1.0f / (1.0f + expf(-racc[bb]));
      const float z = 1.0f / (1.0f + expf(-zacc[bb]));
      const float n = tanhf(gin[bb] + r * ghn[bb]);
      const float hode = sh_in[i][bb];
      const float hnext = (1.0f - z) * n + z * hode;
      const float m = mask[(size_t)(bbase + bb) * TT + t];
      const float hnew = m * hnext + (1.0f - m) * hode;  // masked-out keeps h_ode
      out[((size_t)(bbase + bb) * TT + t) * HH + i] = hnew;
      sh_h[i][bb] = hnew;
    }
    __syncthreads();  // protect sh_x / sh_in / sh_h before next iteration's writes
  }
}

extern "C" void kernel_launch(void* const* d_in, const int* in_sizes, int n_in,
                              void* d_out, int out_size, void* d_ws, size_t ws_size,
                              hipStream_t stream) {
  (void)in_sizes; (void)n_in; (void)d_ws; (void)ws_size; (void)out_size;
  const float* x     = (const float*)d_in[0];
  const float* times = (const float*)d_in[1];
  const float* mask  = (const float*)d_in[2];
  const float* W1    = (const float*)d_in[3];
  const float* b1    = (const float*)d_in[4];
  const float* W2    = (const float*)d_in[5];
  const float* b2    = (const float*)d_in[6];
  const float* Wih   = (const float*)d_in[7];
  const float* bih   = (const float*)d_in[8];
  const float* Whh   = (const float*)d_in[9];
  const float* bhh   = (const float*)d_in[10];
  float* out = (float*)d_out;

  hipLaunchKernelGGL(prep_kernel, dim3((HH * H3 + 255) / 256), dim3(256), 0, stream,
                     W1, W2, Whh, Wih);
  hipLaunchKernelGGL(odegru_kernel, dim3(BN / BB), dim3(HH), 0, stream,
                     x, times, mask, b1, b2, bih, bhh, out);
}